// Round 6
// baseline (750.622 us; speedup 1.0000x reference)
//
#include <hip/hip_runtime.h>
#include <hip/hip_bf16.h>
#include <math.h>

#define B_ 8
#define S_ 1024
#define E_ 1024
#define H_ 16
#define HD_ 64
#define F_ 4096
#define M_ (B_ * S_)   // 8192

typedef float f32x4 __attribute__((ext_vector_type(4)));
typedef short short8 __attribute__((ext_vector_type(8)));

__device__ inline unsigned short f2bf(float x) {
    union { float f; unsigned int u; } v; v.f = x;
    unsigned int r = (v.u + 0x7fffu + ((v.u >> 16) & 1u)) >> 16;
    return (unsigned short)r;
}
__device__ inline float bf2f(unsigned short u) {
    union { unsigned int u; float f; } v; v.u = ((unsigned int)u) << 16;
    return v.f;
}

// inline erf, Abramowitz-Stegun 7.1.26, |err| < 1.5e-7 — NO libcall (erff() is a
// real ABI call on this toolchain: it spilled the MFMA accumulators around 64
// calls/thread in the epilogue -> 6.8 GB of scratch traffic, 1347us dispatch)
__device__ inline float erf_inline(float x) {
    float ax = __builtin_fabsf(x);
    float t = __builtin_amdgcn_rcpf(1.0f + 0.3275911f * ax);
    float y = t * (0.254829592f + t * (-0.284496736f + t * (1.421413741f +
              t * (-1.453152027f + t * 1.061405429f))));
    float e = __expf(-ax * ax);
    float r = 1.0f - y * e;
    union { float f; unsigned int u; } s, o;
    s.f = x; o.f = r;
    o.u = (o.u & 0x7fffffffu) | (s.u & 0x80000000u);
    return o.f;
}

#define AS1 __attribute__((address_space(1)))
#define AS3 __attribute__((address_space(3)))
__device__ inline void gload_lds16(const void* g, void* l) {
    __builtin_amdgcn_global_load_lds((const AS1 unsigned int*)(g),
                                     (AS3 unsigned int*)(l), 16, 0, 0);
}

// ---------------- cast x fp32 -> bf16 ----------------
__global__ __launch_bounds__(256) void cast_f32_bf16(const float* __restrict__ in,
                                                     unsigned short* __restrict__ out) {
    int i = (blockIdx.x * 256 + threadIdx.x) * 4;
    float4 v = *(const float4*)(in + i);
    ushort4 o;
    o.x = f2bf(v.x); o.y = f2bf(v.y); o.z = f2bf(v.z); o.w = f2bf(v.w);
    *(ushort4*)(out + i) = o;
}

// ---------------- mask prep: per (b,s) additive -1e30/0 and q-side 0/1 float ----------------
__global__ __launch_bounds__(256) void mask_prep(const int* __restrict__ am,
                                                 const int* __restrict__ tt,
                                                 float* __restrict__ amqf,
                                                 float* __restrict__ negadd) {
    int i = blockIdx.x * 256 + threadIdx.x;   // i in [0, B*S)
    int s = i & (S_ - 1);
    int a = am[i], t = tt[i];
    amqf[i] = (a != 0) ? 1.0f : 0.0f;
    negadd[i] = ((t == 1) || (a == 0) || (s == 0)) ? -1e30f : 0.0f;
}

// ---------------- transpose+cast weight: in[K,N] f32 -> out[N,K] bf16 ----------------
__global__ __launch_bounds__(256) void transpose_cast(const float* __restrict__ in,
                                                      unsigned short* __restrict__ out,
                                                      int K, int N) {
    __shared__ float tile[32][33];
    int n0 = blockIdx.x * 32, k0 = blockIdx.y * 32;
    int tc = threadIdx.x & 31, tr = threadIdx.x >> 5;  // tr 0..7
    for (int i = 0; i < 4; ++i) {
        int k = k0 + tr + i * 8;
        tile[tr + i * 8][tc] = in[(size_t)k * N + n0 + tc];
    }
    __syncthreads();
    for (int i = 0; i < 4; ++i) {
        int n = n0 + tr + i * 8;
        out[(size_t)n * K + k0 + tc] = f2bf(tile[tc][tr + i * 8]);
    }
}

// ---------------- GEMM: C[M,N] = A[M,K](bf16) @ Bt[N,K]^T(bf16) + bias, epilogues ----------------
// EPI 0: qkv  -> bias, scale cols<1024 by 1/8, store bf16
// EPI 1: gelu -> bias, exact gelu (inline erf), store bf16
// EPI 2: res  -> bias + res[row*N+col], store fp32
#define BM 128
#define BN 128
#define BK 32
template <int EPI>
__global__ __launch_bounds__(256) void gemm_bt(const unsigned short* __restrict__ A,
                                               const unsigned short* __restrict__ Bt,
                                               const float* __restrict__ bias,
                                               const float* __restrict__ res,
                                               unsigned short* __restrict__ Cb,
                                               float* __restrict__ Cf,
                                               int M, int N, int K) {
    __shared__ unsigned short lA[BM * BK];
    __shared__ unsigned short lB[BN * BK];
    int row0 = blockIdx.y * BM, col0 = blockIdx.x * BN;
    int t = threadIdx.x;
    int lane = t & 63, w = t >> 6;
    int wr = w >> 1, wc = w & 1;
    int qa = lane >> 4, ml = lane & 15;

    f32x4 acc[4][4] = {};
    const unsigned short* Aptr = A + (size_t)row0 * K;
    const unsigned short* Bptr = Bt + (size_t)col0 * K;

    for (int k0 = 0; k0 < K; k0 += BK) {
        __syncthreads();
        for (int i = 0; i < 2; ++i) {
            int c = t + i * 256;
            int r = c >> 2, kc = c & 3;
            gload_lds16(Aptr + (size_t)r * K + k0 + kc * 8, lA + c * 8);
            gload_lds16(Bptr + (size_t)r * K + k0 + kc * 8, lB + c * 8);
        }
        __syncthreads();
        short8 af[4], bfr[4];
        for (int i = 0; i < 4; ++i)
            af[i] = *(const short8*)&lA[(wr * 64 + i * 16 + ml) * BK + qa * 8];
        for (int j = 0; j < 4; ++j)
            bfr[j] = *(const short8*)&lB[(wc * 64 + j * 16 + ml) * BK + qa * 8];
        for (int i = 0; i < 4; ++i)
            for (int j = 0; j < 4; ++j)
                acc[i][j] = __builtin_amdgcn_mfma_f32_16x16x32_bf16(af[i], bfr[j], acc[i][j], 0, 0, 0);
    }

    for (int i = 0; i < 4; ++i) {
        for (int j = 0; j < 4; ++j) {
            int col = col0 + wc * 64 + j * 16 + ml;
            float bv = bias[col];
            for (int r = 0; r < 4; ++r) {
                int row = row0 + wr * 64 + i * 16 + qa * 4 + r;
                float cv = acc[i][j][r] + bv;
                if (EPI == 0) {
                    if (col < 1024) cv *= 0.125f;
                    Cb[(size_t)row * N + col] = f2bf(cv);
                } else if (EPI == 1) {
                    cv = 0.5f * cv * (1.0f + erf_inline(cv * 0.70710678118654752f));
                    Cb[(size_t)row * N + col] = f2bf(cv);
                } else {
                    cv += res[(size_t)row * N + col];
                    Cf[(size_t)row * N + col] = cv;
                }
            }
        }
    }
}

// ---------------- transpose v slice of qkv -> vT[b,h,d,s] ----------------
__global__ __launch_bounds__(256) void transpose_v(const unsigned short* __restrict__ qkv,
                                                   unsigned short* __restrict__ vT) {
    __shared__ unsigned short tile[64][72];
    int s0 = blockIdx.x * 64;
    int pair = blockIdx.y;
    int b = pair >> 4, h = pair & 15;
    int t = threadIdx.x;
    int r = t >> 2, c0 = (t & 3) * 16;
    const unsigned short* src = qkv + (size_t)(b * S_ + s0 + r) * 3072 + 2048 + h * 64 + c0;
    *(short8*)&tile[r][c0] = *(const short8*)src;
    *(short8*)&tile[r][c0 + 8] = *(const short8*)(src + 8);
    __syncthreads();
    int d = t >> 2, sc0 = (t & 3) * 16;
    unsigned short tmp[16];
    for (int i = 0; i < 16; ++i) tmp[i] = tile[sc0 + i][d];
    unsigned short* dst = vT + ((size_t)pair * 64 + d) * S_ + s0 + sc0;
    *(short8*)dst = *(const short8*)&tmp[0];
    *(short8*)(dst + 8) = *(const short8*)&tmp[8];
}

// ---------------- flash attention v4: barrier-free, K B-frags direct from global ----------------
// v3 (LDS-staged K, 2 barriers/chunk) was latency-bound: MfmaUtil 7.7%, VALU 30%,
// both idle — the per-chunk serial chain + vmcnt(0) barrier drains coupled all 4
// waves. v4: K loaded per-subtile as B-frags from global (L2-resident, co-issues
// under MFMA), NO __syncthreads anywhere (lP is per-wave), mask folded into the
// MFMA C-initializer. LDS 33.8->17.4 KB: up to 8 blocks/CU.
__global__ __launch_bounds__(256) void attn_flash(const unsigned short* __restrict__ qkv,
                                                  const unsigned short* __restrict__ vT,
                                                  const float* __restrict__ amqf,
                                                  const float* __restrict__ negadd,
                                                  unsigned short* __restrict__ ctx) {
    __shared__ unsigned short lP[4][16 * 136];    // per-wave P tile, stride 136
    int qc = blockIdx.x;                          // 0..15
    int pair = blockIdx.y;
    int b = pair >> 4, h = pair & 15;
    int t = threadIdx.x, w = t >> 6, lane = t & 63;
    int qa = lane >> 4, ml = lane & 15;
    int q0 = qc * 64 + w * 16;                    // wave's first q-row

    // Q A-frags straight from global (row = q0+ml)
    const unsigned short* qrow = qkv + (size_t)(b * S_ + q0 + ml) * 3072 + h * 64;
    short8 aq0 = *(const short8*)(qrow + qa * 8);
    short8 aq1 = *(const short8*)(qrow + 32 + qa * 8);
    float amq[4];
    for (int r = 0; r < 4; ++r) amq[r] = amqf[b * S_ + q0 + qa * 4 + r];

    const unsigned short* kbase = qkv + (size_t)b * S_ * 3072 + 1024 + h * 64 + qa * 8;
    const float* nb = negadd + b * S_;

    float m_old[4] = {-3e38f, -3e38f, -3e38f, -3e38f};
    float l[4] = {0.f, 0.f, 0.f, 0.f};
    f32x4 O[4] = {};
    unsigned short* pw = lP[w];

    for (int kc = 0; kc < 8; ++kc) {
        int kk0 = kc * 128;
        // scores: 8 subtiles of 16 keys; B-frag (key = ks*16+ml, elems qa*8.. / +32)
        f32x4 sacc[8];
        for (int ks = 0; ks < 8; ++ks) {
            int key = kk0 + ks * 16 + ml;
            const unsigned short* kp = kbase + (size_t)key * 3072;
            short8 bb0 = *(const short8*)kp;
            short8 bb1 = *(const short8*)(kp + 32);
            float sb = nb[key];
            f32x4 a;
            for (int r = 0; r < 4; ++r) a[r] = amq[r] + sb;   // mask as C-init
            a = __builtin_amdgcn_mfma_f32_16x16x32_bf16(aq0, bb0, a, 0, 0, 0);
            a = __builtin_amdgcn_mfma_f32_16x16x32_bf16(aq1, bb1, a, 0, 0, 0);
            sacc[ks] = a;
        }
        // online softmax update
        float m_new[4], alpha[4], sum[4];
        for (int r = 0; r < 4; ++r) {
            float m = m_old[r];
            for (int ks = 0; ks < 8; ++ks) m = fmaxf(m, sacc[ks][r]);
            for (int o = 8; o >= 1; o >>= 1) m = fmaxf(m, __shfl_xor(m, o, 16));
            m_new[r] = m;
            alpha[r] = __expf(m_old[r] - m);
            m_old[r] = m;
            sum[r] = 0.f;
        }
        for (int ks = 0; ks < 8; ++ks) {
            for (int r = 0; r < 4; ++r) {
                float p = __expf(sacc[ks][r] - m_new[r]);
                sum[r] += p;
                pw[(qa * 4 + r) * 136 + ks * 16 + ml] = f2bf(p);
            }
        }
        for (int r = 0; r < 4; ++r) {
            float s = sum[r];
            for (int o = 8; o >= 1; o >>= 1) s += __shfl_xor(s, o, 16);
            l[r] = l[r] * alpha[r] + s;
        }
        for (int ds = 0; ds < 4; ++ds)
            for (int r = 0; r < 4; ++r)
                O[ds][r] *= alpha[r];
        // PV: P[16x128] @ V[128x64]  (V via vT rows, contiguous in s)
        for (int ds = 0; ds < 4; ++ds) {
            const unsigned short* vtp = vT + ((size_t)pair * 64 + ds * 16 + ml) * S_ + kk0;
            for (int kst = 0; kst < 4; ++kst) {
                short8 ap = *(const short8*)(pw + ml * 136 + kst * 32 + qa * 8);
                short8 bp = *(const short8*)(vtp + kst * 32 + qa * 8);
                O[ds] = __builtin_amdgcn_mfma_f32_16x16x32_bf16(ap, bp, O[ds], 0, 0, 0);
            }
        }
    }
    // epilogue
    for (int r = 0; r < 4; ++r) {
        float inv = 1.0f / l[r];
        size_t orow = (size_t)(b * S_ + q0 + qa * 4 + r) * E_ + h * 64;
        for (int ds = 0; ds < 4; ++ds)
            ctx[orow + ds * 16 + ml] = f2bf(O[ds][r] * inv);
    }
}

// ---------------- row LayerNorm over E=1024 ----------------
template <int WRITE_BF16>
__global__ __launch_bounds__(256) void ln_kernel(const float* __restrict__ in,
                                                 const float* __restrict__ lw,
                                                 const float* __restrict__ lb,
                                                 float* __restrict__ outf,
                                                 unsigned short* __restrict__ outb) {
    int row = blockIdx.x;
    int t = threadIdx.x;
    const float* x = in + (size_t)row * E_;
    float4 v = ((const float4*)x)[t];
    float s = v.x + v.y + v.z + v.w;
    float sq = v.x * v.x + v.y * v.y + v.z * v.z + v.w * v.w;
    for (int o = 32; o >= 1; o >>= 1) {
        s += __shfl_xor(s, o, 64);
        sq += __shfl_xor(sq, o, 64);
    }
    __shared__ float red[8];
    if ((t & 63) == 0) { red[t >> 6] = s; red[4 + (t >> 6)] = sq; }
    __syncthreads();
    s = red[0] + red[1] + red[2] + red[3];
    sq = red[4] + red[5] + red[6] + red[7];
    float mu = s * (1.0f / E_);
    float var = sq * (1.0f / E_) - mu * mu;
    float rstd = rsqrtf(fmaxf(var, 0.0f) + 1e-12f);
    float4 wv = ((const float4*)lw)[t];
    float4 bv = ((const float4*)lb)[t];
    float4 o;
    o.x = (v.x - mu) * rstd * wv.x + bv.x;
    o.y = (v.y - mu) * rstd * wv.y + bv.y;
    o.z = (v.z - mu) * rstd * wv.z + bv.z;
    o.w = (v.w - mu) * rstd * wv.w + bv.w;
    ((float4*)(outf + (size_t)row * E_))[t] = o;
    if (WRITE_BF16) {
        ushort4 ob;
        ob.x = f2bf(o.x); ob.y = f2bf(o.y); ob.z = f2bf(o.z); ob.w = f2bf(o.w);
        ((ushort4*)(outb + (size_t)row * E_))[t] = ob;
    }
}

extern "C" void kernel_launch(void* const* d_in, const int* in_sizes, int n_in,
                              void* d_out, int out_size, void* d_ws, size_t ws_size,
                              hipStream_t stream) {
    const float* x        = (const float*)d_in[0];
    const int*   am       = (const int*)d_in[1];
    const int*   tt       = (const int*)d_in[2];
    const float* in_w     = (const float*)d_in[3];
    const float* in_b     = (const float*)d_in[4];
    const float* out_w    = (const float*)d_in[5];
    const float* out_b    = (const float*)d_in[6];
    const float* ln_w     = (const float*)d_in[7];
    const float* ln_b     = (const float*)d_in[8];
    const float* w_in     = (const float*)d_in[9];
    const float* b_in     = (const float*)d_in[10];
    const float* w_out    = (const float*)d_in[11];
    const float* b_out    = (const float*)d_in[12];
    float* out = (float*)d_out;

    const size_t MB = 1024 * 1024;
    char* ws = (char*)d_ws;
    unsigned short* xb    = (unsigned short*)(ws + 0);        // 16 MB (reused as hb)
    unsigned short* hb    = xb;
    unsigned short* wqkvT = (unsigned short*)(ws + 16 * MB);  // 6 MB
    unsigned short* woutT = (unsigned short*)(ws + 22 * MB);  // 2 MB
    unsigned short* winT  = (unsigned short*)(ws + 24 * MB);  // 8 MB
    unsigned short* wo2T  = (unsigned short*)(ws + 32 * MB);  // 8 MB
    unsigned short* qkvb  = (unsigned short*)(ws + 40 * MB);  // 48 MB
    unsigned short* vT    = (unsigned short*)(ws + 88 * MB);  // 16 MB
    unsigned short* ctx   = (unsigned short*)(ws + 104 * MB); // 16 MB
    float*          res1  = (float*)(ws + 120 * MB);          // 32 MB (reused for res2)
    float*          hbuf  = (float*)(ws + 152 * MB);          // 32 MB
    unsigned short* ffmid = (unsigned short*)(ws + 184 * MB); // 64 MB  -> total 248 MB
    // mask floats live in the ffmid region (unused until gemm3, attn is done by then)
    float*          amqf  = (float*)(ws + 184 * MB);          // 32 KB
    float*          negadd= (float*)(ws + 185 * MB);          // 32 KB

    // 1. cast x -> bf16; mask prep
    cast_f32_bf16<<<dim3(M_ * E_ / 1024), 256, 0, stream>>>(x, xb);
    mask_prep<<<dim3(M_ / 256), 256, 0, stream>>>(am, tt, amqf, negadd);
    // 2. transpose-cast weights
    transpose_cast<<<dim3(3 * E_ / 32, E_ / 32), 256, 0, stream>>>(in_w, wqkvT, E_, 3 * E_);
    transpose_cast<<<dim3(E_ / 32, E_ / 32), 256, 0, stream>>>(out_w, woutT, E_, E_);
    transpose_cast<<<dim3(F_ / 32, E_ / 32), 256, 0, stream>>>(w_in, winT, E_, F_);
    transpose_cast<<<dim3(E_ / 32, F_ / 32), 256, 0, stream>>>(w_out, wo2T, F_, E_);
    // 3. qkv = x @ in_proj_w + in_proj_b  (q scaled by 1/8)
    gemm_bt<0><<<dim3(3 * E_ / BN, M_ / BM), 256, 0, stream>>>(xb, wqkvT, in_b, nullptr,
                                                               qkvb, nullptr, M_, 3 * E_, E_);
    // 4. vT
    transpose_v<<<dim3(S_ / 64, B_ * H_), 256, 0, stream>>>(qkvb, vT);
    // 5. attention -> ctx
    attn_flash<<<dim3(S_ / 64, B_ * H_), 256, 0, stream>>>(qkvb, vT, amqf, negadd, ctx);
    // 6. attn_out + x  (fp32)
    gemm_bt<2><<<dim3(E_ / BN, M_ / BM), 256, 0, stream>>>(ctx, woutT, out_b, x,
                                                           nullptr, res1, M_, E_, E_);
    // 7. LN1 -> hbuf (f32) + hb (bf16)
    ln_kernel<1><<<dim3(M_), 256, 0, stream>>>(res1, ln_w, ln_b, hbuf, hb);
    // 8. ffmid = gelu(h @ w_in + b_in)
    gemm_bt<1><<<dim3(F_ / BN, M_ / BM), 256, 0, stream>>>(hb, winT, b_in, nullptr,
                                                           ffmid, nullptr, M_, F_, E_);
    // 9. ff + h (fp32)
    gemm_bt<2><<<dim3(E_ / BN, M_ / BM), 256, 0, stream>>>(ffmid, wo2T, b_out, hbuf,
                                                           nullptr, res1, M_, E_, F_);
    // 10. LN2 -> out
    ln_kernel<0><<<dim3(M_), 256, 0, stream>>>(res1, ln_w, ln_b, out, nullptr);
}

// Round 7
// 733.544 us; speedup vs baseline: 1.0233x; 1.0233x over previous
//
#include <hip/hip_runtime.h>
#include <hip/hip_bf16.h>
#include <math.h>

#define B_ 8
#define S_ 1024
#define E_ 1024
#define H_ 16
#define HD_ 64
#define F_ 4096
#define M_ (B_ * S_)   // 8192

typedef float f32x4 __attribute__((ext_vector_type(4)));
typedef short short8 __attribute__((ext_vector_type(8)));

__device__ inline unsigned short f2bf(float x) {
    union { float f; unsigned int u; } v; v.f = x;
    unsigned int r = (v.u + 0x7fffu + ((v.u >> 16) & 1u)) >> 16;
    return (unsigned short)r;
}
__device__ inline float bf2f(unsigned short u) {
    union { unsigned int u; float f; } v; v.u = ((unsigned int)u) << 16;
    return v.f;
}

// inline erf, Abramowitz-Stegun 7.1.26, |err| < 1.5e-7 — NO libcall (erff() is a
// real ABI call on this toolchain: it spilled the MFMA accumulators around 64
// calls/thread in the epilogue -> 6.8 GB of scratch traffic, 1347us dispatch)
__device__ inline float erf_inline(float x) {
    float ax = __builtin_fabsf(x);
    float t = __builtin_amdgcn_rcpf(1.0f + 0.3275911f * ax);
    float y = t * (0.254829592f + t * (-0.284496736f + t * (1.421413741f +
              t * (-1.453152027f + t * 1.061405429f))));
    float e = __expf(-ax * ax);
    float r = 1.0f - y * e;
    union { float f; unsigned int u; } s, o;
    s.f = x; o.f = r;
    o.u = (o.u & 0x7fffffffu) | (s.u & 0x80000000u);
    return o.f;
}

#define AS1 __attribute__((address_space(1)))
#define AS3 __attribute__((address_space(3)))
__device__ inline void gload_lds16(const void* g, void* l) {
    __builtin_amdgcn_global_load_lds((const AS1 unsigned int*)(g),
                                     (AS3 unsigned int*)(l), 16, 0, 0);
}

// ---------------- cast x fp32 -> bf16 ----------------
__global__ __launch_bounds__(256) void cast_f32_bf16(const float* __restrict__ in,
                                                     unsigned short* __restrict__ out) {
    int i = (blockIdx.x * 256 + threadIdx.x) * 4;
    float4 v = *(const float4*)(in + i);
    ushort4 o;
    o.x = f2bf(v.x); o.y = f2bf(v.y); o.z = f2bf(v.z); o.w = f2bf(v.w);
    *(ushort4*)(out + i) = o;
}

// ---------------- mask prep: per (b,s) additive -1e30/0 and q-side 0/1 float ----------------
__global__ __launch_bounds__(256) void mask_prep(const int* __restrict__ am,
                                                 const int* __restrict__ tt,
                                                 float* __restrict__ amqf,
                                                 float* __restrict__ negadd) {
    int i = blockIdx.x * 256 + threadIdx.x;   // i in [0, B*S)
    int s = i & (S_ - 1);
    int a = am[i], t = tt[i];
    amqf[i] = (a != 0) ? 1.0f : 0.0f;
    negadd[i] = ((t == 1) || (a == 0) || (s == 0)) ? -1e30f : 0.0f;
}

// ---------------- transpose+cast weight: in[K,N] f32 -> out[N,K] bf16 ----------------
__global__ __launch_bounds__(256) void transpose_cast(const float* __restrict__ in,
                                                      unsigned short* __restrict__ out,
                                                      int K, int N) {
    __shared__ float tile[32][33];
    int n0 = blockIdx.x * 32, k0 = blockIdx.y * 32;
    int tc = threadIdx.x & 31, tr = threadIdx.x >> 5;  // tr 0..7
    for (int i = 0; i < 4; ++i) {
        int k = k0 + tr + i * 8;
        tile[tr + i * 8][tc] = in[(size_t)k * N + n0 + tc];
    }
    __syncthreads();
    for (int i = 0; i < 4; ++i) {
        int n = n0 + tr + i * 8;
        out[(size_t)n * K + k0 + tc] = f2bf(tile[tc][tr + i * 8]);
    }
}

// ---------------- GEMM: C[M,N] = A[M,K](bf16) @ Bt[N,K]^T(bf16) + bias, epilogues ----------------
// EPI 0: qkv  -> bias, scale cols<1024 by 1/8, store bf16
// EPI 1: gelu -> bias, exact gelu (inline erf), store bf16
// EPI 2: res  -> bias + res[row*N+col], store fp32
#define BM 128
#define BN 128
#define BK 32
template <int EPI>
__global__ __launch_bounds__(256) void gemm_bt(const unsigned short* __restrict__ A,
                                               const unsigned short* __restrict__ Bt,
                                               const float* __restrict__ bias,
                                               const float* __restrict__ res,
                                               unsigned short* __restrict__ Cb,
                                               float* __restrict__ Cf,
                                               int M, int N, int K) {
    __shared__ unsigned short lA[BM * BK];
    __shared__ unsigned short lB[BN * BK];
    int row0 = blockIdx.y * BM, col0 = blockIdx.x * BN;
    int t = threadIdx.x;
    int lane = t & 63, w = t >> 6;
    int wr = w >> 1, wc = w & 1;
    int qa = lane >> 4, ml = lane & 15;

    f32x4 acc[4][4] = {};
    const unsigned short* Aptr = A + (size_t)row0 * K;
    const unsigned short* Bptr = Bt + (size_t)col0 * K;

    for (int k0 = 0; k0 < K; k0 += BK) {
        __syncthreads();
        for (int i = 0; i < 2; ++i) {
            int c = t + i * 256;
            int r = c >> 2, kc = c & 3;
            gload_lds16(Aptr + (size_t)r * K + k0 + kc * 8, lA + c * 8);
            gload_lds16(Bptr + (size_t)r * K + k0 + kc * 8, lB + c * 8);
        }
        __syncthreads();
        short8 af[4], bfr[4];
        for (int i = 0; i < 4; ++i)
            af[i] = *(const short8*)&lA[(wr * 64 + i * 16 + ml) * BK + qa * 8];
        for (int j = 0; j < 4; ++j)
            bfr[j] = *(const short8*)&lB[(wc * 64 + j * 16 + ml) * BK + qa * 8];
        for (int i = 0; i < 4; ++i)
            for (int j = 0; j < 4; ++j)
                acc[i][j] = __builtin_amdgcn_mfma_f32_16x16x32_bf16(af[i], bfr[j], acc[i][j], 0, 0, 0);
    }

    for (int i = 0; i < 4; ++i) {
        for (int j = 0; j < 4; ++j) {
            int col = col0 + wc * 64 + j * 16 + ml;
            float bv = bias[col];
            for (int r = 0; r < 4; ++r) {
                int row = row0 + wr * 64 + i * 16 + qa * 4 + r;
                float cv = acc[i][j][r] + bv;
                if (EPI == 0) {
                    if (col < 1024) cv *= 0.125f;
                    Cb[(size_t)row * N + col] = f2bf(cv);
                } else if (EPI == 1) {
                    cv = 0.5f * cv * (1.0f + erf_inline(cv * 0.70710678118654752f));
                    Cb[(size_t)row * N + col] = f2bf(cv);
                } else {
                    cv += res[(size_t)row * N + col];
                    Cf[(size_t)row * N + col] = cv;
                }
            }
        }
    }
}

// ---------------- transpose v slice of qkv -> vT[b,h,d,s] ----------------
__global__ __launch_bounds__(256) void transpose_v(const unsigned short* __restrict__ qkv,
                                                   unsigned short* __restrict__ vT) {
    __shared__ unsigned short tile[64][72];
    int s0 = blockIdx.x * 64;
    int pair = blockIdx.y;
    int b = pair >> 4, h = pair & 15;
    int t = threadIdx.x;
    int r = t >> 2, c0 = (t & 3) * 16;
    const unsigned short* src = qkv + (size_t)(b * S_ + s0 + r) * 3072 + 2048 + h * 64 + c0;
    *(short8*)&tile[r][c0] = *(const short8*)src;
    *(short8*)&tile[r][c0 + 8] = *(const short8*)(src + 8);
    __syncthreads();
    int d = t >> 2, sc0 = (t & 3) * 16;
    unsigned short tmp[16];
    for (int i = 0; i < 16; ++i) tmp[i] = tile[sc0 + i][d];
    unsigned short* dst = vT + ((size_t)pair * 64 + d) * S_ + s0 + sc0;
    *(short8*)dst = *(const short8*)&tmp[0];
    *(short8*)(dst + 8) = *(const short8*)&tmp[8];
}

// ---------------- flash attention v5: LDS K staging, DOUBLE-buffered, stage-ahead ----------------
// History: v3 (single lK, stage->drain->compute) = 181us, staging latency fully
// exposed between the 2 barriers of each chunk. v4 (K direct from global, no
// barriers) = 249us REGRESSION: L2 latency moved onto the score-MFMA chain and
// K reads quadrupled (per-wave, uncoalesced 6KB stride). v5: keep v3's swizzled
// global_load_lds staging, add lK[2]; per chunk ONE __syncthreads (its vmcnt(0)
// drains loads issued a full chunk ago - already landed), then issue next
// chunk's stage, then compute current. Exposed latency ~0.
__global__ __launch_bounds__(256) void attn_flash(const unsigned short* __restrict__ qkv,
                                                  const unsigned short* __restrict__ vT,
                                                  const float* __restrict__ amqf,
                                                  const float* __restrict__ negadd,
                                                  unsigned short* __restrict__ ctx) {
    __shared__ unsigned short lK[2][128 * 64];    // swizzled [key][slot], 2 x 16 KB
    __shared__ unsigned short lP[4][16 * 136];    // per-wave P tile, stride 136
    int qc = blockIdx.x;                          // 0..15
    int pair = blockIdx.y;
    int b = pair >> 4, h = pair & 15;
    int t = threadIdx.x, w = t >> 6, lane = t & 63;
    int qa = lane >> 4, ml = lane & 15;
    int q0 = qc * 64 + w * 16;                    // wave's first q-row

    // Q A-frags straight from global (row = q0+ml)
    const unsigned short* qrow = qkv + (size_t)(b * S_ + q0 + ml) * 3072 + h * 64;
    short8 aq0 = *(const short8*)(qrow + qa * 8);
    short8 aq1 = *(const short8*)(qrow + 32 + qa * 8);
    float amq[4];
    for (int r = 0; r < 4; ++r) amq[r] = amqf[b * S_ + q0 + qa * 4 + r];

    // staging addresses (chunk c = w*256 + i*64 + lane -> row=c>>3, slot=c&7)
    // XOR source-permute: LDS slot s of row holds global e8-chunk s^(row&7).
    const unsigned short* ksrc[4];
    int kofs[4];
    for (int i = 0; i < 4; ++i) {
        int c = w * 256 + i * 64 + lane;
        int row = c >> 3, slot = c & 7, e8 = slot ^ (row & 7);
        ksrc[i] = qkv + (size_t)(b * S_ + row) * 3072 + 1024 + h * 64 + e8 * 8;
        kofs[i] = c * 8;
    }
    int sw0 = qa ^ (ml & 7);                // slot holding chunk qa of key (key&7 == ml&7)
    int sw1 = (qa + 4) ^ (ml & 7);          // slot holding chunk qa+4

    const float* nb = negadd + b * S_;

    float m_old[4] = {-3e38f, -3e38f, -3e38f, -3e38f};
    float l[4] = {0.f, 0.f, 0.f, 0.f};
    f32x4 O[4] = {};
    unsigned short* pw = lP[w];

    // prologue: stage chunk 0 into buffer 0
    for (int i = 0; i < 4; ++i)
        gload_lds16(ksrc[i], &lK[0][0] + kofs[i]);

    for (int kc = 0; kc < 8; ++kc) {
        int kk0 = kc * 128;
        __syncthreads();   // vmcnt(0) drain: buf[kc&1] loads (issued last iter) complete;
                           // also orders buffer reuse (WAR) across waves
        if (kc < 7) {      // stage-ahead: next chunk flies under this chunk's compute
            const unsigned short* nsrc = (const unsigned short*)((const char*)0);
            (void)nsrc;
            for (int i = 0; i < 4; ++i)
                gload_lds16(ksrc[i] + (size_t)(kk0 + 128) * 3072, &lK[(kc + 1) & 1][0] + kofs[i]);
        }
        const unsigned short* cur = &lK[kc & 1][0];

        // scores: 8 subtiles of 16 keys
        f32x4 sacc[8];
        for (int ks = 0; ks < 8; ++ks) {
            int keyoff = (ks * 16 + ml) * 64;
            short8 bb0 = *(const short8*)(cur + keyoff + sw0 * 8);
            short8 bb1 = *(const short8*)(cur + keyoff + sw1 * 8);
            float sb = nb[kk0 + ks * 16 + ml];
            f32x4 a;
            for (int r = 0; r < 4; ++r) a[r] = amq[r] + sb;   // mask as C-init
            a = __builtin_amdgcn_mfma_f32_16x16x32_bf16(aq0, bb0, a, 0, 0, 0);
            a = __builtin_amdgcn_mfma_f32_16x16x32_bf16(aq1, bb1, a, 0, 0, 0);
            sacc[ks] = a;
        }
        // online softmax update
        float m_new[4], alpha[4], sum[4];
        for (int r = 0; r < 4; ++r) {
            float m = m_old[r];
            for (int ks = 0; ks < 8; ++ks) m = fmaxf(m, sacc[ks][r]);
            for (int o = 8; o >= 1; o >>= 1) m = fmaxf(m, __shfl_xor(m, o, 16));
            m_new[r] = m;
            alpha[r] = __expf(m_old[r] - m);
            m_old[r] = m;
            sum[r] = 0.f;
        }
        for (int ks = 0; ks < 8; ++ks) {
            for (int r = 0; r < 4; ++r) {
                float p = __expf(sacc[ks][r] - m_new[r]);
                sum[r] += p;
                pw[(qa * 4 + r) * 136 + ks * 16 + ml] = f2bf(p);
            }
        }
        for (int r = 0; r < 4; ++r) {
            float s = sum[r];
            for (int o = 8; o >= 1; o >>= 1) s += __shfl_xor(s, o, 16);
            l[r] = l[r] * alpha[r] + s;
        }
        for (int ds = 0; ds < 4; ++ds)
            for (int r = 0; r < 4; ++r)
                O[ds][r] *= alpha[r];
        // PV: P[16x128] @ V[128x64]  (V via vT rows, contiguous in s)
        for (int ds = 0; ds < 4; ++ds) {
            const unsigned short* vtp = vT + ((size_t)pair * 64 + ds * 16 + ml) * S_ + kk0;
            for (int kst = 0; kst < 4; ++kst) {
                short8 ap = *(const short8*)(pw + ml * 136 + kst * 32 + qa * 8);
                short8 bp = *(const short8*)(vtp + kst * 32 + qa * 8);
                O[ds] = __builtin_amdgcn_mfma_f32_16x16x32_bf16(ap, bp, O[ds], 0, 0, 0);
            }
        }
    }
    // epilogue
    for (int r = 0; r < 4; ++r) {
        float inv = 1.0f / l[r];
        size_t orow = (size_t)(b * S_ + q0 + qa * 4 + r) * E_ + h * 64;
        for (int ds = 0; ds < 4; ++ds)
            ctx[orow + ds * 16 + ml] = f2bf(O[ds][r] * inv);
    }
}

// ---------------- row LayerNorm over E=1024 ----------------
template <int WRITE_BF16>
__global__ __launch_bounds__(256) void ln_kernel(const float* __restrict__ in,
                                                 const float* __restrict__ lw,
                                                 const float* __restrict__ lb,
                                                 float* __restrict__ outf,
                                                 unsigned short* __restrict__ outb) {
    int row = blockIdx.x;
    int t = threadIdx.x;
    const float* x = in + (size_t)row * E_;
    float4 v = ((const float4*)x)[t];
    float s = v.x + v.y + v.z + v.w;
    float sq = v.x * v.x + v.y * v.y + v.z * v.z + v.w * v.w;
    for (int o = 32; o >= 1; o >>= 1) {
        s += __shfl_xor(s, o, 64);
        sq += __shfl_xor(sq, o, 64);
    }
    __shared__ float red[8];
    if ((t & 63) == 0) { red[t >> 6] = s; red[4 + (t >> 6)] = sq; }
    __syncthreads();
    s = red[0] + red[1] + red[2] + red[3];
    sq = red[4] + red[5] + red[6] + red[7];
    float mu = s * (1.0f / E_);
    float var = sq * (1.0f / E_) - mu * mu;
    float rstd = rsqrtf(fmaxf(var, 0.0f) + 1e-12f);
    float4 wv = ((const float4*)lw)[t];
    float4 bv = ((const float4*)lb)[t];
    float4 o;
    o.x = (v.x - mu) * rstd * wv.x + bv.x;
    o.y = (v.y - mu) * rstd * wv.y + bv.y;
    o.z = (v.z - mu) * rstd * wv.z + bv.z;
    o.w = (v.w - mu) * rstd * wv.w + bv.w;
    ((float4*)(outf + (size_t)row * E_))[t] = o;
    if (WRITE_BF16) {
        ushort4 ob;
        ob.x = f2bf(o.x); ob.y = f2bf(o.y); ob.z = f2bf(o.z); ob.w = f2bf(o.w);
        ((ushort4*)(outb + (size_t)row * E_))[t] = ob;
    }
}

extern "C" void kernel_launch(void* const* d_in, const int* in_sizes, int n_in,
                              void* d_out, int out_size, void* d_ws, size_t ws_size,
                              hipStream_t stream) {
    const float* x        = (const float*)d_in[0];
    const int*   am       = (const int*)d_in[1];
    const int*   tt       = (const int*)d_in[2];
    const float* in_w     = (const float*)d_in[3];
    const float* in_b     = (const float*)d_in[4];
    const float* out_w    = (const float*)d_in[5];
    const float* out_b    = (const float*)d_in[6];
    const float* ln_w     = (const float*)d_in[7];
    const float* ln_b     = (const float*)d_in[8];
    const float* w_in     = (const float*)d_in[9];
    const float* b_in     = (const float*)d_in[10];
    const float* w_out    = (const float*)d_in[11];
    const float* b_out    = (const float*)d_in[12];
    float* out = (float*)d_out;

    const size_t MB = 1024 * 1024;
    char* ws = (char*)d_ws;
    unsigned short* xb    = (unsigned short*)(ws + 0);        // 16 MB (reused as hb)
    unsigned short* hb    = xb;
    unsigned short* wqkvT = (unsigned short*)(ws + 16 * MB);  // 6 MB
    unsigned short* woutT = (unsigned short*)(ws + 22 * MB);  // 2 MB
    unsigned short* winT  = (unsigned short*)(ws + 24 * MB);  // 8 MB
    unsigned short* wo2T  = (unsigned short*)(ws + 32 * MB);  // 8 MB
    unsigned short* qkvb  = (unsigned short*)(ws + 40 * MB);  // 48 MB
    unsigned short* vT    = (unsigned short*)(ws + 88 * MB);  // 16 MB
    unsigned short* ctx   = (unsigned short*)(ws + 104 * MB); // 16 MB
    float*          res1  = (float*)(ws + 120 * MB);          // 32 MB (reused for res2)
    float*          hbuf  = (float*)(ws + 152 * MB);          // 32 MB
    unsigned short* ffmid = (unsigned short*)(ws + 184 * MB); // 64 MB  -> total 248 MB
    // mask floats live in the ffmid region (unused until gemm3, attn is done by then)
    float*          amqf  = (float*)(ws + 184 * MB);          // 32 KB
    float*          negadd= (float*)(ws + 185 * MB);          // 32 KB

    // 1. cast x -> bf16; mask prep
    cast_f32_bf16<<<dim3(M_ * E_ / 1024), 256, 0, stream>>>(x, xb);
    mask_prep<<<dim3(M_ / 256), 256, 0, stream>>>(am, tt, amqf, negadd);
    // 2. transpose-cast weights
    transpose_cast<<<dim3(3 * E_ / 32, E_ / 32), 256, 0, stream>>>(in_w, wqkvT, E_, 3 * E_);
    transpose_cast<<<dim3(E_ / 32, E_ / 32), 256, 0, stream>>>(out_w, woutT, E_, E_);
    transpose_cast<<<dim3(F_ / 32, E_ / 32), 256, 0, stream>>>(w_in, winT, E_, F_);
    transpose_cast<<<dim3(E_ / 32, F_ / 32), 256, 0, stream>>>(w_out, wo2T, F_, E_);
    // 3. qkv = x @ in_proj_w + in_proj_b  (q scaled by 1/8)
    gemm_bt<0><<<dim3(3 * E_ / BN, M_ / BM), 256, 0, stream>>>(xb, wqkvT, in_b, nullptr,
                                                               qkvb, nullptr, M_, 3 * E_, E_);
    // 4. vT
    transpose_v<<<dim3(S_ / 64, B_ * H_), 256, 0, stream>>>(qkvb, vT);
    // 5. attention -> ctx
    attn_flash<<<dim3(S_ / 64, B_ * H_), 256, 0, stream>>>(qkvb, vT, amqf, negadd, ctx);
    // 6. attn_out + x  (fp32)
    gemm_bt<2><<<dim3(E_ / BN, M_ / BM), 256, 0, stream>>>(ctx, woutT, out_b, x,
                                                           nullptr, res1, M_, E_, E_);
    // 7. LN1 -> hbuf (f32) + hb (bf16)
    ln_kernel<1><<<dim3(M_), 256, 0, stream>>>(res1, ln_w, ln_b, hbuf, hb);
    // 8. ffmid = gelu(h @ w_in + b_in)
    gemm_bt<1><<<dim3(F_ / BN, M_ / BM), 256, 0, stream>>>(hb, winT, b_in, nullptr,
                                                           ffmid, nullptr, M_, F_, E_);
    // 9. ff + h (fp32)
    gemm_bt<2><<<dim3(E_ / BN, M_ / BM), 256, 0, stream>>>(ffmid, wo2T, b_out, hbuf,
                                                           nullptr, res1, M_, E_, F_);
    // 10. LN2 -> out
    ln_kernel<0><<<dim3(M_), 256, 0, stream>>>(res1, ln_w, ln_b, out, nullptr);
}